// Round 1
// 299.201 us; speedup vs baseline: 1.0109x; 1.0109x over previous
//
#include <hip/hip_runtime.h>

#define HW_SHIFT 18               // H*W = 512*512 = 2^18
#define HW (1 << HW_SHIFT)
#define NC 6
#define NIC 3
#define EPS 1e-5f

typedef float f4 __attribute__((ext_vector_type(4)));

// Move a wave-uniform float from VGPR to SGPR so it stops costing occupancy.
__device__ __forceinline__ float uniform_f(float v) {
    return __uint_as_float(__builtin_amdgcn_readfirstlane(__float_as_uint(v)));
}

__global__ __launch_bounds__(256, 8) void aff_softmax_kernel(
    const float* __restrict__ x,
    const float* __restrict__ w1, const float* __restrict__ b1,
    const float* __restrict__ g1, const float* __restrict__ be1,
    const float* __restrict__ m1, const float* __restrict__ v1,
    const float* __restrict__ w2, const float* __restrict__ b2,
    const float* __restrict__ g2, const float* __restrict__ be2,
    const float* __restrict__ m2, const float* __restrict__ v2,
    float* __restrict__ out, int total4)
{
    // ---- Fold BN1 into conv1, BN2 into conv2. All results are wave-uniform;
    // readfirstlane them into SGPRs (45 floats would otherwise eat VGPRs and
    // cap occupancy at ~5 waves/SIMD — we want 8 for latency hiding). ----
    float W1f[NIC][NC], B1f[NIC];
#pragma unroll
    for (int o = 0; o < NIC; ++o) {
        const float inv = g1[o] * rsqrtf(v1[o] + EPS);
        B1f[o] = uniform_f(fmaf(b1[o], inv, be1[o] - m1[o] * inv));
#pragma unroll
        for (int c = 0; c < NC; ++c) W1f[o][c] = uniform_f(w1[o * NC + c] * inv);
    }
    float W2f[NC][NIC], B2f[NC];
#pragma unroll
    for (int o = 0; o < NC; ++o) {
        const float inv = g2[o] * rsqrtf(v2[o] + EPS);
        B2f[o] = uniform_f(fmaf(b2[o], inv, be2[o] - m2[o] * inv));
#pragma unroll
        for (int c = 0; c < NIC; ++c) W2f[o][c] = uniform_f(w2[o * NIC + c] * inv);
    }

    // ---- Grid-stride over float4 pixel groups; 4 pixels per iteration. ----
    const int stride = gridDim.x * blockDim.x;
    for (int g = blockIdx.x * blockDim.x + threadIdx.x; g < total4; g += stride) {
        const int p  = g << 2;                 // first pixel index (global over B*H*W)
        const int b  = p >> HW_SHIFT;          // batch
        const int hw = p & (HW - 1);           // offset within plane
        const float* xb = x + ((long)(b * NC) << HW_SHIFT) + hw;

        // Single-use streaming data: non-temporal to avoid L2 pollution.
        f4 xv[NC];
#pragma unroll
        for (int c = 0; c < NC; ++c)
            xv[c] = __builtin_nontemporal_load((const f4*)(xb + (c << HW_SHIFT)));

        f4 res;
#pragma unroll
        for (int i = 0; i < 4; ++i) {
            // conv1 + BN1 + ReLU  (weights in SGPRs: v_fma_f32 s,v,v)
            float h1[NIC];
#pragma unroll
            for (int o = 0; o < NIC; ++o) {
                float a = B1f[o];
#pragma unroll
                for (int c = 0; c < NC; ++c) a = fmaf(W1f[o][c], xv[c][i], a);
                h1[o] = fmaxf(a, 0.0f);
            }

            // conv2 + BN2 + running max for softmax
            float h2[NC], mx = -3.4e38f;
#pragma unroll
            for (int o = 0; o < NC; ++o) {
                float a = B2f[o];
#pragma unroll
                for (int c = 0; c < NIC; ++c) a = fmaf(W2f[o][c], h1[c], a);
                h2[o] = a;
                mx = fmaxf(mx, a);
            }

            // softmax over channels fused with weighted channel sum
            float sum = 0.0f, acc = 0.0f;
#pragma unroll
            for (int o = 0; o < NC; ++o) {
                const float e = __expf(h2[o] - mx);
                sum += e;
                acc = fmaf(e, xv[o][i], acc);
            }
            res[i] = acc * __builtin_amdgcn_rcpf(sum);  // approx rcp: ~1 ulp, tolerance is 7.8e-3
        }

        __builtin_nontemporal_store(res, (f4*)(out + p));
    }
}

extern "C" void kernel_launch(void* const* d_in, const int* in_sizes, int n_in,
                              void* d_out, int out_size, void* d_ws, size_t ws_size,
                              hipStream_t stream) {
    const float* x   = (const float*)d_in[0];
    const float* w1  = (const float*)d_in[1];
    const float* b1  = (const float*)d_in[2];
    const float* g1  = (const float*)d_in[3];
    const float* be1 = (const float*)d_in[4];
    const float* m1  = (const float*)d_in[5];
    const float* v1  = (const float*)d_in[6];
    const float* w2  = (const float*)d_in[7];
    const float* b2  = (const float*)d_in[8];
    const float* g2  = (const float*)d_in[9];
    const float* be2 = (const float*)d_in[10];
    const float* m2  = (const float*)d_in[11];
    const float* v2  = (const float*)d_in[12];
    float* out = (float*)d_out;

    // out_size = 32*512*512 = 8,388,608 pixels; 4 pixels per float4 group.
    const int threads = 256;
    const int total4  = out_size / 4;          // 2,097,152 groups
    // 2048 blocks = 8 blocks/CU x 4 waves = 32 waves/CU resident (needs <=64 VGPR,
    // enforced by __launch_bounds__(256,8)); each thread grid-strides 4 groups.
    int blocks = 2048;
    const int needed = (total4 + threads - 1) / threads;
    if (blocks > needed) blocks = needed;

    aff_softmax_kernel<<<blocks, threads, 0, stream>>>(
        x, w1, b1, g1, be1, m1, v1, w2, b2, g2, be2, m2, v2, out, total4);
}

// Round 2
// 291.958 us; speedup vs baseline: 1.0359x; 1.0248x over previous
//
#include <hip/hip_runtime.h>

#define HW_SHIFT 18               // H*W = 512*512 = 2^18
#define HW (1 << HW_SHIFT)
#define NC 6
#define NIC 3
#define EPS 1e-5f

typedef float f4 __attribute__((ext_vector_type(4)));

// Move a wave-uniform float from VGPR to SGPR so it stops costing occupancy.
__device__ __forceinline__ float uniform_f(float v) {
    return __uint_as_float(__builtin_amdgcn_readfirstlane(__float_as_uint(v)));
}

// Flat grid: one float4 pixel-group per thread, zero loop overhead, minimal
// live set. 8192 blocks x 256 threads x 4 pixels = 8,388,608 = B*H*W exactly,
// so no bounds guard. No forced occupancy: BW needs only ~9KB in flight/CU,
// any occupancy >=4 waves/SIMD saturates; forcing 64 VGPR risks scratch spill
// (extra HBM traffic) on a BW-bound kernel.
__global__ __launch_bounds__(256) void aff_softmax_kernel(
    const float* __restrict__ x,
    const float* __restrict__ w1, const float* __restrict__ b1,
    const float* __restrict__ g1, const float* __restrict__ be1,
    const float* __restrict__ m1, const float* __restrict__ v1,
    const float* __restrict__ w2, const float* __restrict__ b2,
    const float* __restrict__ g2, const float* __restrict__ be2,
    const float* __restrict__ m2, const float* __restrict__ v2,
    float* __restrict__ out)
{
    // ---- Fold BN1 into conv1, BN2 into conv2; hoist all 45 folded constants
    // to SGPRs via readfirstlane (wave-uniform by construction). ----
    float W1f[NIC][NC], B1f[NIC];
#pragma unroll
    for (int o = 0; o < NIC; ++o) {
        const float inv = g1[o] * rsqrtf(v1[o] + EPS);
        B1f[o] = uniform_f(fmaf(b1[o], inv, be1[o] - m1[o] * inv));
#pragma unroll
        for (int c = 0; c < NC; ++c) W1f[o][c] = uniform_f(w1[o * NC + c] * inv);
    }
    float W2f[NC][NIC], B2f[NC];
#pragma unroll
    for (int o = 0; o < NC; ++o) {
        const float inv = g2[o] * rsqrtf(v2[o] + EPS);
        B2f[o] = uniform_f(fmaf(b2[o], inv, be2[o] - m2[o] * inv));
#pragma unroll
        for (int c = 0; c < NIC; ++c) W2f[o][c] = uniform_f(w2[o * NIC + c] * inv);
    }

    const int g  = blockIdx.x * blockDim.x + threadIdx.x;
    const int p  = g << 2;                 // first pixel index (global over B*H*W)
    const int b  = p >> HW_SHIFT;          // batch
    const int hw = p & (HW - 1);           // offset within plane
    const float* xb = x + ((long)(b * NC) << HW_SHIFT) + hw;

    // Single-use streaming data: non-temporal, skip L2.
    f4 xv[NC];
#pragma unroll
    for (int c = 0; c < NC; ++c)
        xv[c] = __builtin_nontemporal_load((const f4*)(xb + (c << HW_SHIFT)));

    f4 res;
#pragma unroll
    for (int i = 0; i < 4; ++i) {
        // conv1 + BN1 + ReLU  (weights in SGPRs: v_fma_f32 s,v,v)
        float h1[NIC];
#pragma unroll
        for (int o = 0; o < NIC; ++o) {
            float a = B1f[o];
#pragma unroll
            for (int c = 0; c < NC; ++c) a = fmaf(W1f[o][c], xv[c][i], a);
            h1[o] = fmaxf(a, 0.0f);
        }

        // conv2 + BN2 + running max for softmax
        float h2[NC], mx = -3.4e38f;
#pragma unroll
        for (int o = 0; o < NC; ++o) {
            float a = B2f[o];
#pragma unroll
            for (int c = 0; c < NIC; ++c) a = fmaf(W2f[o][c], h1[c], a);
            h2[o] = a;
            mx = fmaxf(mx, a);
        }

        // softmax over channels fused with weighted channel sum
        float sum = 0.0f, acc = 0.0f;
#pragma unroll
        for (int o = 0; o < NC; ++o) {
            const float e = __expf(h2[o] - mx);
            sum += e;
            acc = fmaf(e, xv[o][i], acc);
        }
        res[i] = acc * __builtin_amdgcn_rcpf(sum);  // ~1 ulp; tolerance is 7.8e-3
    }

    __builtin_nontemporal_store(res, (f4*)(out + p));
}

extern "C" void kernel_launch(void* const* d_in, const int* in_sizes, int n_in,
                              void* d_out, int out_size, void* d_ws, size_t ws_size,
                              hipStream_t stream) {
    const float* x   = (const float*)d_in[0];
    const float* w1  = (const float*)d_in[1];
    const float* b1  = (const float*)d_in[2];
    const float* g1  = (const float*)d_in[3];
    const float* be1 = (const float*)d_in[4];
    const float* m1  = (const float*)d_in[5];
    const float* v1  = (const float*)d_in[6];
    const float* w2  = (const float*)d_in[7];
    const float* b2  = (const float*)d_in[8];
    const float* g2  = (const float*)d_in[9];
    const float* be2 = (const float*)d_in[10];
    const float* m2  = (const float*)d_in[11];
    const float* v2  = (const float*)d_in[12];
    float* out = (float*)d_out;

    // out_size = 32*512*512 = 8,388,608 pixels; 4 pixels per thread, flat grid.
    const int threads = 256;
    const int total4  = out_size / 4;                      // 2,097,152 groups
    const int blocks  = (total4 + threads - 1) / threads;  // 8192

    aff_softmax_kernel<<<blocks, threads, 0, stream>>>(
        x, w1, b1, g1, be1, m1, v1, w2, b2, g2, be2, m2, v2, out);
}